// Round 6
// baseline (207.087 us; speedup 1.0000x reference)
//
#include <hip/hip_runtime.h>
#include <hip/hip_bf16.h>
#include <hip/hip_fp16.h>

// Problem constants (B=8, T=4096, Din=Dout=256, WINDOW=2)
#define BDIM 8
#define TDIM 4096
#define DDIM 256
#define MDIM (BDIM * TDIM)      // 32768
#define NCHUNK 256              // chunks along T for the parallel scan
#define LCHUNK (TDIM / NCHUNK)  // 16

typedef _Float16 f16x8 __attribute__((ext_vector_type(8)));
typedef float f32x4 __attribute__((ext_vector_type(4)));

__device__ __forceinline__ float sigmoid_(float x) {
    return 1.0f / (1.0f + __expf(-x));
}

__device__ __forceinline__ f16x8 cvt8(const float4 a, const float4 b) {
    f16x8 r;
    r[0] = (_Float16)a.x; r[1] = (_Float16)a.y;
    r[2] = (_Float16)a.z; r[3] = (_Float16)a.w;
    r[4] = (_Float16)b.x; r[5] = (_Float16)b.y;
    r[6] = (_Float16)b.z; r[7] = (_Float16)b.w;
    return r;
}

// ---------------------------------------------------------------------------
// W[g][w][kin][n] fp32 -> Wt[g][n][w*256+kin] f16 (contiguous in k).
// ---------------------------------------------------------------------------
__global__ __launch_bounds__(256) void convert_w(
    const float* __restrict__ Wz, const float* __restrict__ Wf,
    const float* __restrict__ Wo, _Float16* __restrict__ Wt) {
    const int idx = blockIdx.x * 256 + threadIdx.x;  // < 3*2*256*256
    const int n = idx & 255;
    const int kin = (idx >> 8) & 255;
    const int w = (idx >> 16) & 1;
    const int g = idx >> 17;
    const float* W = (g == 0) ? Wz : (g == 1) ? Wf : Wo;
    const float v = W[(size_t)w * 65536 + (size_t)kin * 256 + n];
    Wt[((size_t)g * 256 + n) * 512 + w * 256 + kin] = (_Float16)v;
}

// ---------------------------------------------------------------------------
// B-RESIDENT MFMA GEMM, zero barriers in the K-loop.
//  - Per job (gate, n-half, 256 rows): stage the 128x256-half B-panel into
//    LDS (64 KB, XOR-swizzled chunks -> conflict-free frag reads, no pad),
//    then each wave streams its A rows (64 x K) DIRECTLY from fp32 x into
//    registers (cvt to f16 in-reg), MFMAs against LDS-resident B.
//    K is split in two 256-half passes (one per conv window tap) so the
//    B-panel is exactly 64 KB; acc persists across passes.
//  - No __syncthreads anywhere in the K-loop -> no vmcnt(0) barrier drain
//    (the m97-structure stall that capped rounds 2-5 at ~70 us).
//  - Wave tile 64 rows x 128 cols = 4x8 frags of 16x16x32 f16 -> 32
//    independent MFMAs per K-step (deep ILP), acc = 128 VGPRs.
//  - Grid 256 blocks x 3 jobs (z, f, o for the SAME m/n-slice -> x rows
//    L2-hot across jobs). 1 block/CU, 4 waves: MFMA-pipe-bound by design.
// ---------------------------------------------------------------------------
__global__ __launch_bounds__(256, 1) void gates_mfma(
    const float* __restrict__ x, const _Float16* __restrict__ Wt,
    const float* __restrict__ bz, const float* __restrict__ bfv,
    const float* __restrict__ bo,
    _Float16* __restrict__ zbuf, _Float16* __restrict__ fbuf,
    _Float16* __restrict__ obuf) {
    const int tid = threadIdx.x;
    const int lane = tid & 63;
    const int wave = tid >> 6;

    __shared__ __align__(16) char smem[65536];
    _Float16* Bs = (_Float16*)smem;

    const int am = lane & 15;   // frag row/col within 16
    const int lq = lane >> 4;   // k-quad 0..3
    const int kq = lq * 8;      // k offset in elements
    const int amx = am & 7;     // xor-swizzle key

    // B staging map: thread covers col = tid&127, 16 chunks of 8 halves.
    const int scol = tid & 127;
    const int sck = (tid >> 7) * 16;

    for (int jr = 0; jr < 3; ++jr) {
        const int j = blockIdx.x + jr * 256;     // 0..767
        const int gate = j >> 8;                 // 0,1,2 (z,f,o)
        const int n0 = ((j >> 7) & 1) * 128;
        const int m0 = (j & 127) * 256;
        const int b = m0 >> 12;
        const int t0 = m0 & (TDIM - 1);
        const float* xb = x + (size_t)b * TDIM * DDIM;

        f32x4 acc[4][8] = {};

        const int twave = t0 + wave * 64;
        const bool edge = (t0 == 0) && (wave == 0);  // wave-uniform

        for (int pass = 0; pass < 2; ++pass) {
            // ---- stage B half-panel: 128 cols x 256 halves = 64 KB ----
            __syncthreads();  // previous reads of Bs done
            {
                const _Float16* src =
                    Wt + ((size_t)gate * 256 + n0 + scol) * 512 + pass * 256 +
                    sck * 8;
                int4 r[16];
#pragma unroll
                for (int i = 0; i < 16; ++i) r[i] = ((const int4*)src)[i];
                _Float16* dstc = Bs + scol * 256;
#pragma unroll
                for (int i = 0; i < 16; ++i)
                    *(int4*)(dstc + (((sck + i) ^ (scol & 7)) << 3)) = r[i];
            }
            __syncthreads();

            // A row pointers: out-row t uses x[t-1+pass] for this k-half.
            const float* arow[4];
#pragma unroll
            for (int rf = 0; rf < 4; ++rf)
                arow[rf] = xb +
                           ((long)(twave + rf * 16 + am) - 1 + pass) * DDIM +
                           kq;
            const bool ep = edge && (pass == 0);  // wave-uniform

            float4 A0[4][2], A1[4][2];

#define LOADA(dst, ks8)                                                      \
    {                                                                        \
        const int kb = (ks8)*32;                                             \
        _Pragma("unroll") for (int rf = 0; rf < 4; ++rf) {                   \
            dst[rf][0] = *(const float4*)(arow[rf] + kb);                    \
            dst[rf][1] = *(const float4*)(arow[rf] + kb + 4);                 \
        }                                                                    \
    }
#define LOADA_EDGE(dst, ks8)                                                 \
    {                                                                        \
        const int kb = (ks8)*32;                                             \
        _Pragma("unroll") for (int rf = 0; rf < 4; ++rf) {                   \
            if (rf == 0 && am == 0) {                                        \
                dst[rf][0] = make_float4(0.f, 0.f, 0.f, 0.f);                \
                dst[rf][1] = make_float4(0.f, 0.f, 0.f, 0.f);                \
            } else {                                                         \
                dst[rf][0] = *(const float4*)(arow[rf] + kb);                \
                dst[rf][1] = *(const float4*)(arow[rf] + kb + 4);             \
            }                                                                \
        }                                                                    \
    }
#define DOMFMA(Abuf, ks8)                                                    \
    {                                                                        \
        f16x8 bb[8];                                                         \
        _Pragma("unroll") for (int cf = 0; cf < 8; ++cf) {                   \
            const int col = cf * 16 + am;                                    \
            const int ch = ((ks8)*4 + lq) ^ amx;                             \
            bb[cf] = *(const f16x8*)(Bs + col * 256 + ch * 8);               \
        }                                                                    \
        f16x8 aa[4];                                                         \
        _Pragma("unroll") for (int rf = 0; rf < 4; ++rf) aa[rf] =            \
            cvt8(Abuf[rf][0], Abuf[rf][1]);                                  \
        _Pragma("unroll") for (int rf = 0; rf < 4; ++rf)                     \
            _Pragma("unroll") for (int cf = 0; cf < 8; ++cf) acc[rf][cf] =   \
                __builtin_amdgcn_mfma_f32_16x16x32_f16(aa[rf], bb[cf],       \
                                                       acc[rf][cf], 0, 0, 0);\
    }

            if (ep) { LOADA_EDGE(A0, 0) } else { LOADA(A0, 0) }
            for (int ks8 = 0; ks8 < 8; ks8 += 2) {
                if (ep) { LOADA_EDGE(A1, ks8 + 1) } else { LOADA(A1, ks8 + 1) }
                DOMFMA(A0, ks8)
                if (ks8 + 2 < 8) {
                    if (ep) { LOADA_EDGE(A0, ks8 + 2) } else { LOADA(A0, ks8 + 2) }
                }
                DOMFMA(A1, ks8 + 1)
            }
#undef LOADA
#undef LOADA_EDGE
#undef DOMFMA
        }  // pass

        // ---- epilogue: all waves done with Bs -> reuse as repack region ----
        __syncthreads();
        const float* bias = (gate == 0) ? bz : (gate == 1) ? bfv : bo;
        _Float16* outp = (gate == 0) ? zbuf : (gate == 1) ? fbuf : obuf;
        // unified activation: a/(1+exp(s*v)) - c  (tanh: a=2,s=-2,c=1; sig: 1,-1,0)
        const float amul = (gate == 0) ? 2.f : 1.f;
        const float smul = (gate == 0) ? -2.f : -1.f;
        const float asub = (gate == 0) ? 1.f : 0.f;

        _Float16* eb = (_Float16*)smem + wave * 8192;  // 64 rows x 128 halves
        float bj[8];
#pragma unroll
        for (int cf = 0; cf < 8; ++cf) bj[cf] = bias[n0 + cf * 16 + am];
        const int rq = lq * 4;
#pragma unroll
        for (int rf = 0; rf < 4; ++rf)
#pragma unroll
            for (int cf = 0; cf < 8; ++cf) {
                f32x4 v = acc[rf][cf];
#pragma unroll
                for (int r = 0; r < 4; ++r) {
                    const float val = v[r] + bj[cf];
                    const float act =
                        amul / (1.f + __expf(smul * val)) - asub;
                    eb[(rf * 16 + rq + r) * 128 + cf * 16 + am] =
                        (_Float16)act;
                }
            }
        // wave-private region: lgkm ordering handled by compiler waits
#pragma unroll
        for (int i = 0; i < 16; ++i) {
            const int flat = i * 64 + lane;
            const int row = flat >> 4;
            const int ch = flat & 15;
            f16x8 v = *(const f16x8*)(eb + row * 128 + ch * 8);
            *(f16x8*)(outp + (size_t)(m0 + wave * 64 + row) * DDIM + n0 +
                      ch * 8) = v;
        }
    }  // jr
}

// ---------------------------------------------------------------------------
// Scan pass 1: per-chunk aggregates over LCHUNK steps from c=0; A = prod(f).
// ---------------------------------------------------------------------------
__global__ __launch_bounds__(256) void scan_pass1(
    const _Float16* __restrict__ zbuf, const _Float16* __restrict__ fbuf,
    float* __restrict__ aggA, float* __restrict__ aggB) {
    const int idx = blockIdx.x * 256 + threadIdx.x;  // < B*NCHUNK*32 = 65536
    const int d8 = idx & 31;
    const int chunk = (idx >> 5) & (NCHUNK - 1);
    const int b = idx >> 13;

    const size_t row0 = (size_t)b * TDIM + (size_t)chunk * LCHUNK;
    const int4* zp = (const int4*)zbuf + row0 * 32 + d8;
    const int4* fp = (const int4*)fbuf + row0 * 32 + d8;

    float A[8], c[8];
#pragma unroll
    for (int e = 0; e < 8; ++e) { A[e] = 1.0f; c[e] = 0.0f; }

#pragma unroll
    for (int i = 0; i < LCHUNK; ++i) {
        int4 fv = *fp;
        int4 zv = *zp;
        const _Float16* fh = (const _Float16*)&fv;
        const _Float16* zh = (const _Float16*)&zv;
#pragma unroll
        for (int e = 0; e < 8; ++e) {
            const float f = (float)fh[e];
            const float z = (float)zh[e];
            A[e] *= f;
            c[e] = f * c[e] + (1.0f - f) * z;
        }
        fp += 32;
        zp += 32;
    }
    ((float4*)aggA)[(size_t)idx * 2 + 0] = make_float4(A[0], A[1], A[2], A[3]);
    ((float4*)aggA)[(size_t)idx * 2 + 1] = make_float4(A[4], A[5], A[6], A[7]);
    ((float4*)aggB)[(size_t)idx * 2 + 0] = make_float4(c[0], c[1], c[2], c[3]);
    ((float4*)aggB)[(size_t)idx * 2 + 1] = make_float4(c[4], c[5], c[6], c[7]);
}

// ---------------------------------------------------------------------------
// Carry scan across chunks: one thread per (b,d) = 2048 threads, unroll-8.
// ---------------------------------------------------------------------------
__global__ __launch_bounds__(256) void carry_scan(
    const float* __restrict__ aggA, const float* __restrict__ aggB,
    float* __restrict__ carry) {
    const int g = blockIdx.x * 256 + threadIdx.x;  // < B*D = 2048
    const int d = g & 255;
    const int b = g >> 8;
    const size_t base = (size_t)b * NCHUNK * 256 + d;

    float c = 0.0f;
    for (int ch0 = 0; ch0 < NCHUNK; ch0 += 8) {
        float A[8], Bv[8];
#pragma unroll
        for (int u = 0; u < 8; ++u) {
            const size_t p = base + (size_t)(ch0 + u) * 256;
            A[u] = aggA[p];
            Bv[u] = aggB[p];
        }
#pragma unroll
        for (int u = 0; u < 8; ++u) {
            const size_t p = base + (size_t)(ch0 + u) * 256;
            carry[p] = c;
            c = A[u] * c + Bv[u];
        }
    }
}

// ---------------------------------------------------------------------------
// Scan pass 2: replay chunk with true carry; h = o*c -> fp32 out.
// ---------------------------------------------------------------------------
__global__ __launch_bounds__(256) void scan_pass2(
    const _Float16* __restrict__ zbuf, const _Float16* __restrict__ fbuf,
    const _Float16* __restrict__ obuf, const float* __restrict__ carry,
    float* __restrict__ out) {
    const int idx = blockIdx.x * 256 + threadIdx.x;  // < 65536
    const int d8 = idx & 31;
    const int chunk = (idx >> 5) & (NCHUNK - 1);
    const int b = idx >> 13;

    float c[8];
    float4 c0 = ((const float4*)carry)[(size_t)idx * 2];
    float4 c1 = ((const float4*)carry)[(size_t)idx * 2 + 1];
    c[0] = c0.x; c[1] = c0.y; c[2] = c0.z; c[3] = c0.w;
    c[4] = c1.x; c[5] = c1.y; c[6] = c1.z; c[7] = c1.w;

    const size_t row0 = (size_t)b * TDIM + (size_t)chunk * LCHUNK;
    const int4* zp = (const int4*)zbuf + row0 * 32 + d8;
    const int4* fp = (const int4*)fbuf + row0 * 32 + d8;
    const int4* op = (const int4*)obuf + row0 * 32 + d8;
    float4* hp = (float4*)out + row0 * 64 + d8 * 2;

#pragma unroll
    for (int i = 0; i < LCHUNK; ++i) {
        int4 fv = *fp;
        int4 zv = *zp;
        int4 ov = *op;
        const _Float16* fh = (const _Float16*)&fv;
        const _Float16* zh = (const _Float16*)&zv;
        const _Float16* oh = (const _Float16*)&ov;
        float h[8];
#pragma unroll
        for (int e = 0; e < 8; ++e) {
            const float f = (float)fh[e];
            const float z = (float)zh[e];
            c[e] = f * c[e] + (1.0f - f) * z;
            h[e] = (float)oh[e] * c[e];
        }
        hp[0] = make_float4(h[0], h[1], h[2], h[3]);
        hp[1] = make_float4(h[4], h[5], h[6], h[7]);
        fp += 32;
        zp += 32;
        op += 32;
        hp += 64;
    }
}

extern "C" void kernel_launch(void* const* d_in, const int* in_sizes, int n_in,
                              void* d_out, int out_size, void* d_ws,
                              size_t ws_size, hipStream_t stream) {
    const float* x = (const float*)d_in[0];
    const float* Wz = (const float*)d_in[1];
    const float* Wf = (const float*)d_in[2];
    const float* Wo = (const float*)d_in[3];
    const float* bz = (const float*)d_in[4];
    const float* bfv = (const float*)d_in[5];
    const float* bo = (const float*)d_in[6];
    float* out = (float*)d_out;

    // Workspace (bytes): Wt 0.79M | z 16.78M | f 16.78M | o 16.78M |
    // aggA 2M | aggB 2M | carry 2M   -> ~57.1 MB (proven scale)
    char* p = (char*)d_ws;
    _Float16* Wt = (_Float16*)p;    p += (size_t)3 * 256 * 512 * 2;
    _Float16* zbuf = (_Float16*)p;  p += (size_t)MDIM * DDIM * 2;
    _Float16* fbuf = (_Float16*)p;  p += (size_t)MDIM * DDIM * 2;
    _Float16* obuf = (_Float16*)p;  p += (size_t)MDIM * DDIM * 2;
    float* aggA = (float*)p;        p += (size_t)BDIM * NCHUNK * DDIM * 4;
    float* aggB = (float*)p;        p += (size_t)BDIM * NCHUNK * DDIM * 4;
    float* carry = (float*)p;

    convert_w<<<(3 * 2 * 256 * 256) / 256, 256, 0, stream>>>(Wz, Wf, Wo, Wt);

    gates_mfma<<<256, 256, 0, stream>>>(x, Wt, bz, bfv, bo, zbuf, fbuf, obuf);

    scan_pass1<<<(BDIM * NCHUNK * 32) / 256, 256, 0, stream>>>(zbuf, fbuf,
                                                               aggA, aggB);
    carry_scan<<<(BDIM * DDIM) / 256, 256, 0, stream>>>(aggA, aggB, carry);
    scan_pass2<<<(BDIM * NCHUNK * 32) / 256, 256, 0, stream>>>(zbuf, fbuf,
                                                               obuf, carry, out);
}